// Round 4
// baseline (8650.658 us; speedup 1.0000x reference)
//
#include <hip/hip_runtime.h>

// Problem constants
#define B_ 64
#define S_ 64
#define T_ 64
#define V_ 32000
#define D_ 512
#define H_ 1024
#define L_ 256

typedef _Float16 f16;
typedef __attribute__((ext_vector_type(4))) _Float16 f16x4;
typedef __attribute__((ext_vector_type(8))) _Float16 f16x8;
typedef __attribute__((ext_vector_type(16))) float f32x16;

#define INV2048 (1.0f / 2048.0f)

// ---------------------------------------------------------------------------
// Pack fp32 weight rows [N][K] into MFMA B-fragment-major f16 hi/lo arrays.
// Frag layout for v_mfma_f32_32x32x16_f16 B-operand:
//   n = nt*32 + (lane&31), k = ks*16 + (lane>>5)*8 + e
//   array: [nt][ks = K/16][lane 64][e 8]
// lo scaled by 2048 to stay in f16 normal range.
// ---------------------------------------------------------------------------
template <int K>
__global__ __launch_bounds__(256) void k_pack_wf(
    const float* __restrict__ W, f16* __restrict__ Bhi, f16* __restrict__ Blo)
{
  const int n = blockIdx.x;
  const int k = threadIdx.x * 4;
  if (k >= K) return;
  float4 w = *reinterpret_cast<const float4*>(W + (long long)n * K + k);
  float wv[4] = {w.x, w.y, w.z, w.w};
  f16x4 hi, lo;
#pragma unroll
  for (int i = 0; i < 4; ++i) {
    const f16 h = (f16)wv[i];
    hi[i] = h;
    lo[i] = (f16)((wv[i] - (float)h) * 2048.0f);
  }
  const int nt = n >> 5;
  const int lane = (n & 31) + 32 * ((k >> 3) & 1);
  const int ks = k >> 4;
  const long long off = (((long long)nt * (K / 16) + ks) * 64 + lane) * 8 + (k & 7);
  *reinterpret_cast<f16x4*>(Bhi + off) = hi;
  *reinterpret_cast<f16x4*>(Blo + off) = lo;
}

// ---------------------------------------------------------------------------
// Unified MFMA GRU step. grid = 32 blocks (one per 32 h-cols) x 384 threads
// (6 waves = 3 gates x 2 K-halves). f16x3 split: preact = M + (La+Lb)/2048.
// Phase 1: hh-part (K=1024) from pre-packed h A-frags + W_hh B-frags.
// Phase 2: ih-part (K=512) from E-row gather (fp32 -> hi/lo on the fly).
// Epilogue: gate math in-kernel, writes hT_out + next-step A-frags.
// XMODE: 0 = no input (decoder t=0), 1 = tokens from int array (stride S_),
//        2 = tokens folded from bestPart partial-argmax keys.
// ---------------------------------------------------------------------------
template <int XMODE>
__global__ __launch_bounds__(384) void k_gru_mfma(
    const float* __restrict__ E, const int* __restrict__ toki,
    const unsigned long long* __restrict__ bp,
    const f16* __restrict__ Whh_hi, const f16* __restrict__ Whh_lo,
    const f16* __restrict__ Wih_hi, const f16* __restrict__ Wih_lo,
    const float* __restrict__ b_ih, const float* __restrict__ b_hh,
    const float* __restrict__ hT_in, float* __restrict__ hT_out,
    const f16* __restrict__ Ahi, const f16* __restrict__ Alo,
    f16* __restrict__ Aohi, f16* __restrict__ Aolo)
{
  constexpr int NPH = (XMODE == 0) ? 1 : 2;
  __shared__ float pre[NPH][2][3][64][33];  // padded: apply reads stride 33
  __shared__ int toks[64];
  const int tid = threadIdx.x;
  const int lane = tid & 63;
  const int wv = __builtin_amdgcn_readfirstlane(tid >> 6);
  const int kh = wv & 1;
  const int g = wv >> 1;
  const int jt = blockIdx.x;
  const int nt = g * 32 + jt;

  // ---- tokens ----
  if constexpr (XMODE == 1) {
    if (tid < 64) toks[tid] = toki[tid * S_];
  } else if constexpr (XMODE == 2) {
    for (int r = wv; r < 64; r += 6) {
      unsigned long long kk = 0ull;
#pragma unroll
      for (int i = 0; i < 4; ++i) {
        const unsigned long long q = bp[(long long)r * 256 + lane + i * 64];
        if (q > kk) kk = q;
      }
#pragma unroll
      for (int m = 1; m < 64; m <<= 1) {
        const unsigned long long q = __shfl_xor(kk, m, 64);
        if (q > kk) kk = q;
      }
      if (lane == 0) toks[r] = (int)(0xFFFFFFFFu - (unsigned)(kk & 0xFFFFFFFFull));
    }
  }

  f32x16 aM0, aM1, aLa0, aLa1, aLb0, aLb1;
#pragma unroll
  for (int i = 0; i < 16; ++i) {
    aM0[i] = 0.f; aM1[i] = 0.f; aLa0[i] = 0.f; aLa1[i] = 0.f; aLb0[i] = 0.f; aLb1[i] = 0.f;
  }

  // ---- phase 1: hidden part, K = 1024 (this wave: 32 k-steps) ----
  {
    const f16x8* bhp = reinterpret_cast<const f16x8*>(Whh_hi) + ((long long)nt * 64 + kh * 32) * 64 + lane;
    const f16x8* blp = reinterpret_cast<const f16x8*>(Whh_lo) + ((long long)nt * 64 + kh * 32) * 64 + lane;
    const f16x8* ahp = reinterpret_cast<const f16x8*>(Ahi) + (long long)(kh * 32) * 64 + lane;
    const f16x8* alp = reinterpret_cast<const f16x8*>(Alo) + (long long)(kh * 32) * 64 + lane;
#pragma unroll 4
    for (int q = 0; q < 32; ++q) {
      const int o = q * 64;
      f16x8 bh = bhp[o];
      f16x8 bl = blp[o];
      f16x8 a0 = ahp[o];
      f16x8 a1 = ahp[4096 + o];
      f16x8 l0 = alp[o];
      f16x8 l1 = alp[4096 + o];
      aM0 = __builtin_amdgcn_mfma_f32_32x32x16_f16(a0, bh, aM0, 0, 0, 0);
      aM1 = __builtin_amdgcn_mfma_f32_32x32x16_f16(a1, bh, aM1, 0, 0, 0);
      aLa0 = __builtin_amdgcn_mfma_f32_32x32x16_f16(a0, bl, aLa0, 0, 0, 0);
      aLa1 = __builtin_amdgcn_mfma_f32_32x32x16_f16(a1, bl, aLa1, 0, 0, 0);
      aLb0 = __builtin_amdgcn_mfma_f32_32x32x16_f16(l0, bh, aLb0, 0, 0, 0);
      aLb1 = __builtin_amdgcn_mfma_f32_32x32x16_f16(l1, bh, aLb1, 0, 0, 0);
    }
  }
  {
    const int jc = lane & 31;
    const int rbase = 4 * (lane >> 5);
#pragma unroll
    for (int reg = 0; reg < 16; ++reg) {
      const int row = (reg & 3) + 8 * (reg >> 2) + rbase;
      pre[0][kh][g][row][jc] = aM0[reg] + (aLa0[reg] + aLb0[reg]) * INV2048;
      pre[0][kh][g][row + 32][jc] = aM1[reg] + (aLa1[reg] + aLb1[reg]) * INV2048;
    }
  }

  __syncthreads();  // toks visible for phase 2

  // ---- phase 2: input part, K = 512 (this wave: 16 k-steps) ----
  if constexpr (XMODE != 0) {
#pragma unroll
    for (int i = 0; i < 16; ++i) {
      aM0[i] = 0.f; aM1[i] = 0.f; aLa0[i] = 0.f; aLa1[i] = 0.f; aLb0[i] = 0.f; aLb1[i] = 0.f;
    }
    const f16x8* bhp = reinterpret_cast<const f16x8*>(Wih_hi) + ((long long)nt * 32 + kh * 16) * 64 + lane;
    const f16x8* blp = reinterpret_cast<const f16x8*>(Wih_lo) + ((long long)nt * 32 + kh * 16) * 64 + lane;
    const int b0 = lane & 31;
    const int khalf = (lane >> 5) * 8;
#pragma unroll 2
    for (int q = 0; q < 16; ++q) {
      const int ks2 = kh * 16 + q;
      f16x8 bh = bhp[q * 64];
      f16x8 bl = blp[q * 64];
      f16x8 a0, l0, a1, l1;
      {
        const float* ep = E + (long long)toks[b0] * D_ + ks2 * 16 + khalf;
        float4 v0 = *reinterpret_cast<const float4*>(ep);
        float4 v1 = *reinterpret_cast<const float4*>(ep + 4);
        float vv[8] = {v0.x, v0.y, v0.z, v0.w, v1.x, v1.y, v1.z, v1.w};
#pragma unroll
        for (int e = 0; e < 8; ++e) { const f16 h = (f16)vv[e]; a0[e] = h; l0[e] = (f16)((vv[e] - (float)h) * 2048.f); }
      }
      {
        const float* ep = E + (long long)toks[32 + b0] * D_ + ks2 * 16 + khalf;
        float4 v0 = *reinterpret_cast<const float4*>(ep);
        float4 v1 = *reinterpret_cast<const float4*>(ep + 4);
        float vv[8] = {v0.x, v0.y, v0.z, v0.w, v1.x, v1.y, v1.z, v1.w};
#pragma unroll
        for (int e = 0; e < 8; ++e) { const f16 h = (f16)vv[e]; a1[e] = h; l1[e] = (f16)((vv[e] - (float)h) * 2048.f); }
      }
      aM0 = __builtin_amdgcn_mfma_f32_32x32x16_f16(a0, bh, aM0, 0, 0, 0);
      aM1 = __builtin_amdgcn_mfma_f32_32x32x16_f16(a1, bh, aM1, 0, 0, 0);
      aLa0 = __builtin_amdgcn_mfma_f32_32x32x16_f16(a0, bl, aLa0, 0, 0, 0);
      aLa1 = __builtin_amdgcn_mfma_f32_32x32x16_f16(a1, bl, aLa1, 0, 0, 0);
      aLb0 = __builtin_amdgcn_mfma_f32_32x32x16_f16(l0, bh, aLb0, 0, 0, 0);
      aLb1 = __builtin_amdgcn_mfma_f32_32x32x16_f16(l1, bh, aLb1, 0, 0, 0);
    }
    const int jc = lane & 31;
    const int rbase = 4 * (lane >> 5);
#pragma unroll
    for (int reg = 0; reg < 16; ++reg) {
      const int row = (reg & 3) + 8 * (reg >> 2) + rbase;
      pre[NPH - 1][kh][g][row][jc] = aM0[reg] + (aLa0[reg] + aLb0[reg]) * INV2048;
      pre[NPH - 1][kh][g][row + 32][jc] = aM1[reg] + (aLa1[reg] + aLb1[reg]) * INV2048;
    }
  }

  __syncthreads();

  // ---- apply: gates + h_out + frag pack ----
  for (int idx = tid; idx < 2048; idx += 384) {
    const int b = idx & 63;
    const int jc = idx >> 6;
    const int j = jt * 32 + jc;
    float rh = pre[0][0][0][b][jc] + pre[0][1][0][b][jc];
    float zh = pre[0][0][1][b][jc] + pre[0][1][1][b][jc];
    float nh = pre[0][0][2][b][jc] + pre[0][1][2][b][jc];
    float rx = 0.f, zx = 0.f, nx = 0.f;
    if constexpr (XMODE != 0) {
      rx = pre[1][0][0][b][jc] + pre[1][1][0][b][jc];
      zx = pre[1][0][1][b][jc] + pre[1][1][1][b][jc];
      nx = pre[1][0][2][b][jc] + pre[1][1][2][b][jc];
    }
    const float gr = rh + rx + b_ih[j] + b_hh[j];
    const float gz = zh + zx + b_ih[H_ + j] + b_hh[H_ + j];
    const float ghn = nh + b_hh[2 * H_ + j];
    const float gin = nx + b_ih[2 * H_ + j];
    const float r = 1.f / (1.f + expf(-gr));
    const float z = 1.f / (1.f + expf(-gz));
    const float n = tanhf(fmaf(r, ghn, gin));
    const float hp = hT_in[j * 64 + b];
    const float hv = (1.f - z) * n + z * hp;
    hT_out[j * 64 + b] = hv;
    const f16 hi = (f16)hv;
    const f16 lo = (f16)((hv - (float)hi) * 2048.f);
    const long long fo = (((long long)(b >> 5) * 64 + (j >> 4)) * 64 + ((b & 31) + 32 * ((j >> 3) & 1))) * 8 + (j & 7);
    Aohi[fo] = hi;
    Aolo[fo] = lo;
  }
}

// ---------------------------------------------------------------------------
// MFMA f16x3 logits GEMM + fused partial argmax (unchanged from round 3).
// grid=250 x 256. Wave owns 32 vocab cols x 64 batch rows; operands stream
// from L2/L3-resident frag arrays; partial keys to bestPart (no atomics).
// ---------------------------------------------------------------------------
__global__ __launch_bounds__(256) void k_logits3(
    const f16* __restrict__ Ahi, const f16* __restrict__ Alo,
    const f16* __restrict__ Bhi, const f16* __restrict__ Blo,
    const float* __restrict__ b_out, float* __restrict__ out,
    unsigned long long* __restrict__ bestPart, int t)
{
  __shared__ float cand[4][64][32];
  __shared__ unsigned long long wbest[4][64];
  const int tid = threadIdx.x;
  const int lane = tid & 63;
  const int wv = __builtin_amdgcn_readfirstlane(tid >> 6);
  const int nt = blockIdx.x * 4 + wv;

  f32x16 accM0, accM1, accL0, accL1;
#pragma unroll
  for (int i = 0; i < 16; ++i) { accM0[i] = 0.f; accM1[i] = 0.f; accL0[i] = 0.f; accL1[i] = 0.f; }

  const f16x8* pAh0 = reinterpret_cast<const f16x8*>(Ahi) + lane;
  const f16x8* pAh1 = reinterpret_cast<const f16x8*>(Ahi) + 4096 + lane;
  const f16x8* pAl0 = reinterpret_cast<const f16x8*>(Alo) + lane;
  const f16x8* pAl1 = reinterpret_cast<const f16x8*>(Alo) + 4096 + lane;
  const f16x8* pBh = reinterpret_cast<const f16x8*>(Bhi) + (long long)nt * 4096 + lane;
  const f16x8* pBl = reinterpret_cast<const f16x8*>(Blo) + (long long)nt * 4096 + lane;

#pragma unroll 4
  for (int ks = 0; ks < 64; ++ks) {
    const int o = ks * 64;
    f16x8 bh = pBh[o];
    f16x8 bl = pBl[o];
    f16x8 ah0 = pAh0[o];
    f16x8 ah1 = pAh1[o];
    f16x8 al0 = pAl0[o];
    f16x8 al1 = pAl1[o];
    accM0 = __builtin_amdgcn_mfma_f32_32x32x16_f16(ah0, bh, accM0, 0, 0, 0);
    accM1 = __builtin_amdgcn_mfma_f32_32x32x16_f16(ah1, bh, accM1, 0, 0, 0);
    accL0 = __builtin_amdgcn_mfma_f32_32x32x16_f16(ah0, bl, accL0, 0, 0, 0);
    accL1 = __builtin_amdgcn_mfma_f32_32x32x16_f16(ah1, bl, accL1, 0, 0, 0);
    accL0 = __builtin_amdgcn_mfma_f32_32x32x16_f16(al0, bh, accL0, 0, 0, 0);
    accL1 = __builtin_amdgcn_mfma_f32_32x32x16_f16(al1, bh, accL1, 0, 0, 0);
  }

  const int nn = nt * 32 + (lane & 31);
  const float bo = b_out[nn];
  const int rbase = 4 * (lane >> 5);
#pragma unroll
  for (int reg = 0; reg < 16; ++reg) {
    const int row0 = (reg & 3) + 8 * (reg >> 2) + rbase;
    const float v0 = accM0[reg] + accL0[reg] * INV2048 + bo;
    out[(long long)row0 * (T_ * (long long)V_) + (long long)t * V_ + nn] = v0;
    cand[wv][row0][lane & 31] = v0;
    const int row1 = row0 + 32;
    const float v1 = accM1[reg] + accL1[reg] * INV2048 + bo;
    out[(long long)row1 * (T_ * (long long)V_) + (long long)t * V_ + nn] = v1;
    cand[wv][row1][lane & 31] = v1;
  }
  __syncthreads();
  {
    const int w = tid >> 6, r = tid & 63;
    const int nb = (blockIdx.x * 4 + w) * 32;
    unsigned long long kk = 0ull;
#pragma unroll
    for (int l0 = 0; l0 < 32; ++l0) {
      const int l = (l0 + r) & 31;
      const float v = cand[w][r][l];
      unsigned u = __float_as_uint(v);
      u = (u & 0x80000000u) ? ~u : (u | 0x80000000u);
      const unsigned long long key = ((unsigned long long)u << 32) |
          (unsigned long long)(0xFFFFFFFFu - (unsigned)(nb + l));
      if (key > kk) kk = key;
    }
    wbest[w][r] = kk;
  }
  __syncthreads();
  if (tid < 64) {
    unsigned long long kk = wbest[0][tid];
#pragma unroll
    for (int w = 1; w < 4; ++w) { const unsigned long long q = wbest[w][tid]; if (q > kk) kk = q; }
    bestPart[(long long)tid * 256 + blockIdx.x] = kk;
  }
}

// ---------------------------------------------------------------------------
// mu / logvar / z from hT (scalar-uniform). grid=64 x 256; wave = latent l.
// ---------------------------------------------------------------------------
__global__ __launch_bounds__(256) void k_mu_lv_z(
    const float* __restrict__ hT, const float* __restrict__ W_mu, const float* __restrict__ b_mu,
    const float* __restrict__ W_lv, const float* __restrict__ b_lv,
    const float* __restrict__ eps, float* __restrict__ out_mu, float* __restrict__ out_lv,
    float* __restrict__ zT)
{
  const int lane = threadIdx.x & 63;
  const int wv = __builtin_amdgcn_readfirstlane(threadIdx.x >> 6);
  const int l = blockIdx.x * 4 + wv;
  const float* wm = W_mu + (long long)l * H_;
  const float* wl = W_lv + (long long)l * H_;
  float am = 0.f, av = 0.f;
#pragma unroll 8
  for (int k = 0; k < H_; ++k) {
    const float h = hT[k * 64 + lane];
    am = fmaf(wm[k], h, am);
    av = fmaf(wl[k], h, av);
  }
  const float mu = am + b_mu[l];
  const float lv = av + b_lv[l];
  out_mu[lane * L_ + l] = mu;
  out_lv[lane * L_ + l] = lv;
  zT[l * 64 + lane] = fmaf(eps[lane * L_ + l], expf(0.5f * lv), mu);
}

// ---------------------------------------------------------------------------
// h_dec0 = z @ W_proj.T + b_proj, from zT; writes hT0 + A-frags.
// grid=256 x 256; wave = hidden col j.
// ---------------------------------------------------------------------------
__global__ __launch_bounds__(256) void k_proj(
    const float* __restrict__ zT, const float* __restrict__ W_proj,
    const float* __restrict__ b_proj, float* __restrict__ hT0,
    f16* __restrict__ Aohi, f16* __restrict__ Aolo)
{
  const int lane = threadIdx.x & 63;
  const int wv = __builtin_amdgcn_readfirstlane(threadIdx.x >> 6);
  const int j = blockIdx.x * 4 + wv;
  const float* wr = W_proj + (long long)j * L_;
  float acc = 0.f;
#pragma unroll 8
  for (int k = 0; k < L_; ++k) acc = fmaf(wr[k], zT[k * 64 + lane], acc);
  const float hv = acc + b_proj[j];
  hT0[j * 64 + lane] = hv;
  const int b = lane;
  const f16 hi = (f16)hv;
  const f16 lo = (f16)((hv - (float)hi) * 2048.f);
  const long long fo = (((long long)(b >> 5) * 64 + (j >> 4)) * 64 + ((b & 31) + 32 * ((j >> 3) & 1))) * 8 + (j & 7);
  Aohi[fo] = hi;
  Aolo[fo] = lo;
}

// ---------------------------------------------------------------------------
extern "C" void kernel_launch(void* const* d_in, const int* in_sizes, int n_in,
                              void* d_out, int out_size, void* d_ws, size_t ws_size,
                              hipStream_t stream) {
  (void)in_sizes; (void)n_in; (void)out_size;
  const int*   x        = (const int*)d_in[0];
  const float* eps      = (const float*)d_in[1];
  const float* E        = (const float*)d_in[2];
  const float* W_ih_enc = (const float*)d_in[3];
  const float* W_hh_enc = (const float*)d_in[4];
  const float* b_ih_enc = (const float*)d_in[5];
  const float* b_hh_enc = (const float*)d_in[6];
  const float* W_mu     = (const float*)d_in[7];
  const float* b_mu     = (const float*)d_in[8];
  const float* W_lv     = (const float*)d_in[9];
  const float* b_lv     = (const float*)d_in[10];
  const float* W_proj   = (const float*)d_in[11];
  const float* b_proj   = (const float*)d_in[12];
  const float* W_ih_dec = (const float*)d_in[13];
  const float* W_hh_dec = (const float*)d_in[14];
  const float* b_ih_dec = (const float*)d_in[15];
  const float* b_hh_dec = (const float*)d_in[16];
  const float* W_out    = (const float*)d_in[17];
  const float* b_out    = (const float*)d_in[18];

  float* out = (float*)d_out;
  const long long OFF_MU = (long long)B_ * T_ * V_;
  const long long OFF_LV = OFF_MU + (long long)B_ * L_;

  // Workspace layout (float offsets)
  float* ws = (float*)d_ws;
  float* hTA  = ws + 0;        // [1024][64]
  float* hTB  = ws + 65536;
  float* hTdA = ws + 131072;
  float* hTdB = ws + 196608;
  float* zT   = ws + 262144;   // [256][64]
  unsigned long long* bestPart = (unsigned long long*)(ws + 278528);  // [64][256]
  f16* frAhi = (f16*)(ws + 311296);   // h A-frags [2][64][64][8]
  f16* frAlo = (f16*)(ws + 344064);
  f16* frBhi = (f16*)(ws + 376832);
  f16* frBlo = (f16*)(ws + 409600);
  f16* WHEhi = (f16*)(ws + 442368);   // W_hh_enc frags [96][64][64][8]
  f16* WHElo = (f16*)(ws + 2015232);
  f16* WHDhi = (f16*)(ws + 3588096);
  f16* WHDlo = (f16*)(ws + 5160960);
  f16* WIEhi = (f16*)(ws + 6733824);  // W_ih frags [96][32][64][8]
  f16* WIElo = (f16*)(ws + 7520256);
  f16* WIDhi = (f16*)(ws + 8306688);
  f16* WIDlo = (f16*)(ws + 9093120);
  f16* WOhi  = (f16*)(ws + 9879552);  // W_out frags [1000][64][64][8]
  f16* WOlo  = (f16*)(ws + 26263552);
  const size_t WS_NEED = (size_t)42647552 * 4;
  if (ws_size < WS_NEED) return;  // harness provided >= 183 MB in prior rounds

  hipMemsetAsync(hTA, 0, (size_t)H_ * B_ * sizeof(float), stream);
  hipMemsetAsync(frAhi, 0, (size_t)2 * 65536 * sizeof(f16), stream);  // frAhi+frAlo
  hipMemsetAsync(bestPart, 0, (size_t)64 * 256 * 8, stream);

  // ---- one-time weight packs ----
  k_pack_wf<1024><<<3 * H_, 256, 0, stream>>>(W_hh_enc, WHEhi, WHElo);
  k_pack_wf<1024><<<3 * H_, 256, 0, stream>>>(W_hh_dec, WHDhi, WHDlo);
  k_pack_wf<512><<<3 * H_, 128, 0, stream>>>(W_ih_enc, WIEhi, WIElo);
  k_pack_wf<512><<<3 * H_, 128, 0, stream>>>(W_ih_dec, WIDhi, WIDlo);
  k_pack_wf<1024><<<V_, 256, 0, stream>>>(W_out, WOhi, WOlo);

  // ---- encoder: 64 MFMA GRU steps ----
  for (int t = 0; t < S_; ++t) {
    const float* hin = (t & 1) ? hTB : hTA;
    float* hout = (t & 1) ? hTA : hTB;
    const f16* fih = (t & 1) ? frBhi : frAhi;
    const f16* fil = (t & 1) ? frBlo : frAlo;
    f16* foh = (t & 1) ? frAhi : frBhi;
    f16* fol = (t & 1) ? frAlo : frBlo;
    k_gru_mfma<1><<<32, 384, 0, stream>>>(
        E, x + t, nullptr, WHEhi, WHElo, WIEhi, WIElo,
        b_ih_enc, b_hh_enc, hin, hout, fih, fil, foh, fol);
  }
  // S_=64 even -> final h in hTA

  // ---- latent ----
  k_mu_lv_z<<<64, 256, 0, stream>>>(hTA, W_mu, b_mu, W_lv, b_lv, eps,
                                    out + OFF_MU, out + OFF_LV, zT);
  k_proj<<<256, 256, 0, stream>>>(zT, W_proj, b_proj, hTdA, frAhi, frAlo);

  // ---- decoder: 64 x (MFMA GRU + MFMA logits w/ fused argmax) ----
  for (int t = 0; t < T_; ++t) {
    const float* hin = (t & 1) ? hTdB : hTdA;
    float* hout = (t & 1) ? hTdA : hTdB;
    const f16* fih = (t & 1) ? frBhi : frAhi;
    const f16* fil = (t & 1) ? frBlo : frAlo;
    f16* foh = (t & 1) ? frAhi : frBhi;
    f16* fol = (t & 1) ? frAlo : frBlo;
    if (t == 0) {
      k_gru_mfma<0><<<32, 384, 0, stream>>>(
          E, nullptr, nullptr, WHDhi, WHDlo, WIDhi, WIDlo,
          b_ih_dec, b_hh_dec, hin, hout, fih, fil, foh, fol);
    } else {
      k_gru_mfma<2><<<32, 384, 0, stream>>>(
          E, nullptr, bestPart, WHDhi, WHDlo, WIDhi, WIDlo,
          b_ih_dec, b_hh_dec, hin, hout, fih, fil, foh, fol);
    }
    k_logits3<<<250, 256, 0, stream>>>(foh, fol, WOhi, WOlo, b_out, out, bestPart, t);
  }
}

// Round 5
// 6076.252 us; speedup vs baseline: 1.4237x; 1.4237x over previous
//
#include <hip/hip_runtime.h>

// Problem constants
#define B_ 64
#define S_ 64
#define T_ 64
#define V_ 32000
#define D_ 512
#define H_ 1024
#define L_ 256

typedef _Float16 f16;
typedef __attribute__((ext_vector_type(4))) _Float16 f16x4;
typedef __attribute__((ext_vector_type(8))) _Float16 f16x8;
typedef __attribute__((ext_vector_type(16))) float f32x16;

#define INV2048 (1.0f / 2048.0f)

// ---------------------------------------------------------------------------
// f16 hi/lo frag write for h values (A-operand layout, m=b, k=j):
// unit = ((b>>5)*64 + (j>>4))*64 + ((b&31) + 32*((j>>3)&1)), elem = j&7
// ---------------------------------------------------------------------------
__device__ __forceinline__ void write_frag(f16* __restrict__ Aohi, f16* __restrict__ Aolo,
                                           int b, int j, float hv) {
  const f16 hi = (f16)hv;
  const f16 lo = (f16)((hv - (float)hi) * 2048.0f);
  const long long fo =
      (((long long)(b >> 5) * 64 + (j >> 4)) * 64 + ((b & 31) + 32 * ((j >> 3) & 1))) * 8 + (j & 7);
  Aohi[fo] = hi;
  Aolo[fo] = lo;
}

// ---------------------------------------------------------------------------
// Pack fp32 weights [N][K] into MFMA B-frag-major f16 hi/lo.
// n = nt*32 + (lane&31), k = ks*16 + (lane>>5)*8 + e; array [nt][K/16][64][8].
// ---------------------------------------------------------------------------
template <int K>
__global__ __launch_bounds__(256) void k_pack_wf(
    const float* __restrict__ W, f16* __restrict__ Bhi, f16* __restrict__ Blo)
{
  const int n = blockIdx.x;
  const int k = threadIdx.x * 4;
  if (k >= K) return;
  float4 w = *reinterpret_cast<const float4*>(W + (long long)n * K + k);
  float wv[4] = {w.x, w.y, w.z, w.w};
  f16x4 hi, lo;
#pragma unroll
  for (int i = 0; i < 4; ++i) {
    const f16 h = (f16)wv[i];
    hi[i] = h;
    lo[i] = (f16)((wv[i] - (float)h) * 2048.0f);
  }
  const int nt = n >> 5;
  const int lane = (n & 31) + 32 * ((k >> 3) & 1);
  const int ks = k >> 4;
  const long long off = (((long long)nt * (K / 16) + ks) * 64 + lane) * 8 + (k & 7);
  *reinterpret_cast<f16x4*>(Bhi + off) = hi;
  *reinterpret_cast<f16x4*>(Blo + off) = lo;
}

// ---------------------------------------------------------------------------
// Pack encoder token embeddings into A-frags. m = s*64+b (4096 rows, K=512).
// grid = 4096 x 128.
// ---------------------------------------------------------------------------
__global__ __launch_bounds__(128) void k_pack_xe(
    const int* __restrict__ x, const float* __restrict__ E,
    f16* __restrict__ XAhi, f16* __restrict__ XAlo)
{
  const int m = blockIdx.x;
  const int s = m >> 6, b = m & 63;
  const int k = threadIdx.x * 4;
  const long long tok = x[b * S_ + s];
  float4 w = *reinterpret_cast<const float4*>(E + tok * D_ + k);
  float wv[4] = {w.x, w.y, w.z, w.w};
  f16x4 hi, lo;
#pragma unroll
  for (int i = 0; i < 4; ++i) {
    const f16 h = (f16)wv[i];
    hi[i] = h;
    lo[i] = (f16)((wv[i] - (float)h) * 2048.0f);
  }
  const int mt = m >> 5;
  const int lane = (m & 31) + 32 * ((k >> 3) & 1);
  const int ks = k >> 4;
  const long long off = (((long long)mt * 32 + ks) * 64 + lane) * 8 + (k & 7);
  *reinterpret_cast<f16x4*>(XAhi + off) = hi;
  *reinterpret_cast<f16x4*>(XAlo + off) = lo;
}

// ---------------------------------------------------------------------------
// Encoder input-gates GEMM via MFMA f16x3:
// Gi[s][n][b] = xe[s,b,:] . W_ih[n,:] + b_ih[n].
// grid = 64 s * 24 ngroups = 1536 blocks x 256 (4 waves, wave owns nt).
// ---------------------------------------------------------------------------
__global__ __launch_bounds__(256) void k_gates_mfma(
    const f16* __restrict__ XAhi, const f16* __restrict__ XAlo,
    const f16* __restrict__ Bhi, const f16* __restrict__ Blo,
    const float* __restrict__ b_ih, float* __restrict__ Gi)
{
  __shared__ float cand[4][64][33];
  const int tid = threadIdx.x;
  const int lane = tid & 63;
  const int wv = __builtin_amdgcn_readfirstlane(tid >> 6);
  const int s = blockIdx.x / 24;
  const int ng = blockIdx.x % 24;
  const int nt = ng * 4 + wv;

  f32x16 aM0, aM1, aLa0, aLa1, aLb0, aLb1;
#pragma unroll
  for (int i = 0; i < 16; ++i) {
    aM0[i] = 0.f; aM1[i] = 0.f; aLa0[i] = 0.f; aLa1[i] = 0.f; aLb0[i] = 0.f; aLb1[i] = 0.f;
  }

  const f16x8* pB_h = reinterpret_cast<const f16x8*>(Bhi) + ((long long)nt * 32) * 64 + lane;
  const f16x8* pB_l = reinterpret_cast<const f16x8*>(Blo) + ((long long)nt * 32) * 64 + lane;
  const f16x8* pA_h = reinterpret_cast<const f16x8*>(XAhi) + ((long long)s * 64) * 64 + lane;
  const f16x8* pA_l = reinterpret_cast<const f16x8*>(XAlo) + ((long long)s * 64) * 64 + lane;

#pragma unroll 4
  for (int ks = 0; ks < 32; ++ks) {
    const int o = ks * 64;
    f16x8 bh = pB_h[o];
    f16x8 bl = pB_l[o];
    f16x8 a0 = pA_h[o];
    f16x8 a1 = pA_h[o + 32 * 64];
    f16x8 l0 = pA_l[o];
    f16x8 l1 = pA_l[o + 32 * 64];
    aM0 = __builtin_amdgcn_mfma_f32_32x32x16_f16(a0, bh, aM0, 0, 0, 0);
    aM1 = __builtin_amdgcn_mfma_f32_32x32x16_f16(a1, bh, aM1, 0, 0, 0);
    aLa0 = __builtin_amdgcn_mfma_f32_32x32x16_f16(a0, bl, aLa0, 0, 0, 0);
    aLa1 = __builtin_amdgcn_mfma_f32_32x32x16_f16(a1, bl, aLa1, 0, 0, 0);
    aLb0 = __builtin_amdgcn_mfma_f32_32x32x16_f16(l0, bh, aLb0, 0, 0, 0);
    aLb1 = __builtin_amdgcn_mfma_f32_32x32x16_f16(l1, bh, aLb1, 0, 0, 0);
  }

  {
    const int l = lane & 31;
    const int rbase = 4 * (lane >> 5);
#pragma unroll
    for (int reg = 0; reg < 16; ++reg) {
      const int row = (reg & 3) + 8 * (reg >> 2) + rbase;
      cand[wv][row][l] = aM0[reg] + (aLa0[reg] + aLb0[reg]) * INV2048;
      cand[wv][row + 32][l] = aM1[reg] + (aLa1[reg] + aLb1[reg]) * INV2048;
    }
  }
  __syncthreads();
  const int bn0 = ng * 128;
#pragma unroll
  for (int i = 0; i < 8; ++i) {
    const int idx = i * 256 + tid;
    const int b4 = (idx & 15) * 4;
    const int nl = idx >> 4;  // 0..127
    const float bi = b_ih[bn0 + nl];
    float4 o;
    o.x = cand[nl >> 5][b4 + 0][nl & 31] + bi;
    o.y = cand[nl >> 5][b4 + 1][nl & 31] + bi;
    o.z = cand[nl >> 5][b4 + 2][nl & 31] + bi;
    o.w = cand[nl >> 5][b4 + 3][nl & 31] + bi;
    *reinterpret_cast<float4*>(&Gi[((long long)s * (3 * H_) + bn0 + nl) * 64 + b4]) = o;
  }
}

// ---------------------------------------------------------------------------
// hh pre-activations via MFMA: preH[n][b] = h[b,:] . W_hh[n,:], n in [0,3H).
// grid = 96 blocks (nt) x 256 (4 waves = K-slices of 256). K=1024.
// ---------------------------------------------------------------------------
__global__ __launch_bounds__(256) void k_hh_mfma(
    const f16* __restrict__ Ahi, const f16* __restrict__ Alo,
    const f16* __restrict__ Bhi, const f16* __restrict__ Blo,
    float* __restrict__ preH)
{
  __shared__ float cand[4][64][33];
  const int tid = threadIdx.x;
  const int lane = tid & 63;
  const int wv = __builtin_amdgcn_readfirstlane(tid >> 6);
  const int nt = blockIdx.x;

  f32x16 aM0, aM1, aLa0, aLa1, aLb0, aLb1;
#pragma unroll
  for (int i = 0; i < 16; ++i) {
    aM0[i] = 0.f; aM1[i] = 0.f; aLa0[i] = 0.f; aLa1[i] = 0.f; aLb0[i] = 0.f; aLb1[i] = 0.f;
  }

  const f16x8* pB_h = reinterpret_cast<const f16x8*>(Bhi) + ((long long)nt * 64 + wv * 16) * 64 + lane;
  const f16x8* pB_l = reinterpret_cast<const f16x8*>(Blo) + ((long long)nt * 64 + wv * 16) * 64 + lane;
  const f16x8* pA_h = reinterpret_cast<const f16x8*>(Ahi) + (long long)(wv * 16) * 64 + lane;
  const f16x8* pA_l = reinterpret_cast<const f16x8*>(Alo) + (long long)(wv * 16) * 64 + lane;

#pragma unroll 4
  for (int q = 0; q < 16; ++q) {
    const int o = q * 64;
    f16x8 bh = pB_h[o];
    f16x8 bl = pB_l[o];
    f16x8 a0 = pA_h[o];
    f16x8 a1 = pA_h[o + 4096];
    f16x8 l0 = pA_l[o];
    f16x8 l1 = pA_l[o + 4096];
    aM0 = __builtin_amdgcn_mfma_f32_32x32x16_f16(a0, bh, aM0, 0, 0, 0);
    aM1 = __builtin_amdgcn_mfma_f32_32x32x16_f16(a1, bh, aM1, 0, 0, 0);
    aLa0 = __builtin_amdgcn_mfma_f32_32x32x16_f16(a0, bl, aLa0, 0, 0, 0);
    aLa1 = __builtin_amdgcn_mfma_f32_32x32x16_f16(a1, bl, aLa1, 0, 0, 0);
    aLb0 = __builtin_amdgcn_mfma_f32_32x32x16_f16(l0, bh, aLb0, 0, 0, 0);
    aLb1 = __builtin_amdgcn_mfma_f32_32x32x16_f16(l1, bh, aLb1, 0, 0, 0);
  }

  {
    const int l = lane & 31;
    const int rbase = 4 * (lane >> 5);
#pragma unroll
    for (int reg = 0; reg < 16; ++reg) {
      const int row = (reg & 3) + 8 * (reg >> 2) + rbase;
      cand[wv][row][l] = aM0[reg] + (aLa0[reg] + aLb0[reg]) * INV2048;
      cand[wv][row + 32][l] = aM1[reg] + (aLa1[reg] + aLb1[reg]) * INV2048;
    }
  }
  __syncthreads();
#pragma unroll
  for (int i = 0; i < 8; ++i) {
    const int idx = i * 256 + tid;  // 0..2047
    const int b = idx & 63;
    const int l = idx >> 6;  // 0..31
    const float v = cand[0][b][l] + cand[1][b][l] + cand[2][b][l] + cand[3][b][l];
    preH[((long long)nt * 32 + l) * 64 + b] = v;
  }
}

// ---------------------------------------------------------------------------
// Encoder apply: gates from preH + Gi_t, writes hT_out + next A-frags.
// grid = 256 x 256 (one elem per thread).
// ---------------------------------------------------------------------------
__global__ __launch_bounds__(256) void k_apply_enc(
    const float* __restrict__ preH, const float* __restrict__ Gi_t,
    const float* __restrict__ b_hh,
    const float* __restrict__ hT_in, float* __restrict__ hT_out,
    f16* __restrict__ Aohi, f16* __restrict__ Aolo)
{
  const int idx = blockIdx.x * 256 + threadIdx.x;
  const int b = idx & 63;
  const int j = idx >> 6;
  const float gr = preH[(long long)j * 64 + b] + Gi_t[(long long)j * 64 + b] + b_hh[j];
  const float gz = preH[(long long)(H_ + j) * 64 + b] + Gi_t[(long long)(H_ + j) * 64 + b] + b_hh[H_ + j];
  const float gin = Gi_t[(long long)(2 * H_ + j) * 64 + b];  // b_ih folded in Gi
  const float ghn = preH[(long long)(2 * H_ + j) * 64 + b] + b_hh[2 * H_ + j];
  const float r = 1.f / (1.f + expf(-gr));
  const float z = 1.f / (1.f + expf(-gz));
  const float n = tanhf(fmaf(r, ghn, gin));
  const float hp = hT_in[(long long)j * 64 + b];
  const float hv = (1.f - z) * n + z * hp;
  hT_out[(long long)j * 64 + b] = hv;
  write_frag(Aohi, Aolo, b, j, hv);
}

// ---------------------------------------------------------------------------
// Decoder apply: fold partial argmax -> toks, fp32 ih-part (K=512) from
// gathered E rows, apply gates with preH (hh computed by k_logits_hh of the
// previous step). grid = 256 blocks (4 j each) x 1024 (16 waves: jj x ks).
// XMODE: 0 = zero input (t=0), 2 = fold bestPart.
// ---------------------------------------------------------------------------
template <int XMODE>
__global__ __launch_bounds__(1024) void k_dec_apply(
    const float* __restrict__ E, const unsigned long long* __restrict__ bp,
    const float* __restrict__ W_ih,
    const float* __restrict__ b_ih, const float* __restrict__ b_hh,
    const float* __restrict__ preH, const float* __restrict__ hT_in,
    float* __restrict__ hT_out, f16* __restrict__ Aohi, f16* __restrict__ Aolo)
{
  __shared__ float4 a_lds[64 * 64];
  __shared__ float red[12 * 3 * 64];
  __shared__ int toks[64];
  const int tid = threadIdx.x;
  const int lane = tid & 63;
  const int wv = __builtin_amdgcn_readfirstlane(tid >> 6);
  const int jj = wv & 3;
  const int ks = wv >> 2;
  const int j = blockIdx.x * 4 + jj;
  const int kf16 = tid & 63;
  const int msub = tid >> 6;

  float accR = 0.f, accZ = 0.f, accIN = 0.f;

  if constexpr (XMODE == 2) {
#pragma unroll
    for (int rr = 0; rr < 4; ++rr) {
      const int r = wv + rr * 16;
      unsigned long long kk = 0ull;
#pragma unroll
      for (int i = 0; i < 4; ++i) {
        const unsigned long long q = bp[(long long)r * 256 + lane + i * 64];
        if (q > kk) kk = q;
      }
#pragma unroll
      for (int m = 1; m < 64; m <<= 1) {
        const unsigned long long q = __shfl_xor(kk, m, 64);
        if (q > kk) kk = q;
      }
      if (lane == 0) toks[r] = (int)(0xFFFFFFFFu - (unsigned)(kk & 0xFFFFFFFFull));
    }
    __syncthreads();

    const float* wr = W_ih + (long long)j * D_;
    const float* wz = W_ih + (long long)(j + H_) * D_;
    const float* wn = W_ih + (long long)(j + 2 * H_) * D_;
    for (int c = 0; c < 2; ++c) {
      __syncthreads();
#pragma unroll
      for (int p = 0; p < 4; ++p) {
        const int m = p * 16 + msub;
        const long long tok = toks[m];
        float4 v = *reinterpret_cast<const float4*>(E + tok * D_ + c * 256 + kf16 * 4);
        a_lds[m * 64 + (kf16 ^ (m & 7))] = v;
      }
      __syncthreads();
#pragma unroll 4
      for (int q = 0; q < 16; ++q) {
        const int kf = ks * 16 + q;
        float4 a = a_lds[lane * 64 + (kf ^ (lane & 7))];
        float4 w0 = *reinterpret_cast<const float4*>(wr + c * 256 + kf * 4);
        float4 w1 = *reinterpret_cast<const float4*>(wz + c * 256 + kf * 4);
        float4 w2 = *reinterpret_cast<const float4*>(wn + c * 256 + kf * 4);
        accR = fmaf(w0.x, a.x, accR); accR = fmaf(w0.y, a.y, accR);
        accR = fmaf(w0.z, a.z, accR); accR = fmaf(w0.w, a.w, accR);
        accZ = fmaf(w1.x, a.x, accZ); accZ = fmaf(w1.y, a.y, accZ);
        accZ = fmaf(w1.z, a.z, accZ); accZ = fmaf(w1.w, a.w, accZ);
        accIN = fmaf(w2.x, a.x, accIN); accIN = fmaf(w2.y, a.y, accIN);
        accIN = fmaf(w2.z, a.z, accIN); accIN = fmaf(w2.w, a.w, accIN);
      }
    }
  }

  if (ks > 0) {
    float* rp = red + (((ks - 1) * 4 + jj) * 3) * 64 + lane;
    rp[0] = accR; rp[64] = accZ; rp[128] = accIN;
  }
  __syncthreads();
  if (ks == 0) {
#pragma unroll
    for (int t2 = 0; t2 < 3; ++t2) {
      const float* rp = red + ((t2 * 4 + jj) * 3) * 64 + lane;
      accR += rp[0]; accZ += rp[64]; accIN += rp[128];
    }
    const float gr = accR + preH[(long long)j * 64 + lane] + b_ih[j] + b_hh[j];
    const float gz = accZ + preH[(long long)(H_ + j) * 64 + lane] + b_ih[H_ + j] + b_hh[H_ + j];
    const float gin = accIN + b_ih[2 * H_ + j];
    const float ghn = preH[(long long)(2 * H_ + j) * 64 + lane] + b_hh[2 * H_ + j];
    const float r = 1.f / (1.f + expf(-gr));
    const float z = 1.f / (1.f + expf(-gz));
    const float n = tanhf(fmaf(r, ghn, gin));
    const float hp = hT_in[(long long)j * 64 + lane];
    const float hv = (1.f - z) * n + z * hp;
    hT_out[(long long)j * 64 + lane] = hv;
    write_frag(Aohi, Aolo, lane, j, hv);
  }
}

// ---------------------------------------------------------------------------
// Fused logits + next-step hh. grid = 274 x 256.
// Blocks [0,250): logits f16x3 GEMM + NT out stores + partial argmax keys.
// Blocks [250,274): hh pre-activations for the NEXT GRU step (same A-frags).
// ---------------------------------------------------------------------------
__global__ __launch_bounds__(256) void k_logits_hh(
    const f16* __restrict__ Ahi, const f16* __restrict__ Alo,
    const f16* __restrict__ WOhi, const f16* __restrict__ WOlo,
    const f16* __restrict__ WHhi, const f16* __restrict__ WHlo,
    const float* __restrict__ b_out, float* __restrict__ out,
    unsigned long long* __restrict__ bestPart, float* __restrict__ preH, int t)
{
  __shared__ float cand[4][64][33];
  __shared__ unsigned long long wbest[4][64];
  const int tid = threadIdx.x;
  const int lane = tid & 63;
  const int wv = __builtin_amdgcn_readfirstlane(tid >> 6);

  if (blockIdx.x >= 250) {
    // ---- hh part: preH[n][b] for next step ----
    const int hhb = blockIdx.x - 250;
    const int nt = hhb * 4 + wv;  // 0..95
    f32x16 aM0, aM1, aLa0, aLa1, aLb0, aLb1;
#pragma unroll
    for (int i = 0; i < 16; ++i) {
      aM0[i] = 0.f; aM1[i] = 0.f; aLa0[i] = 0.f; aLa1[i] = 0.f; aLb0[i] = 0.f; aLb1[i] = 0.f;
    }
    const f16x8* pB_h = reinterpret_cast<const f16x8*>(WHhi) + ((long long)nt * 64) * 64 + lane;
    const f16x8* pB_l = reinterpret_cast<const f16x8*>(WHlo) + ((long long)nt * 64) * 64 + lane;
    const f16x8* pA_h = reinterpret_cast<const f16x8*>(Ahi) + lane;
    const f16x8* pA_l = reinterpret_cast<const f16x8*>(Alo) + lane;
#pragma unroll 4
    for (int ksi = 0; ksi < 64; ++ksi) {
      const int o = ksi * 64;
      f16x8 bh = pB_h[o];
      f16x8 bl = pB_l[o];
      f16x8 a0 = pA_h[o];
      f16x8 a1 = pA_h[o + 4096];
      f16x8 l0 = pA_l[o];
      f16x8 l1 = pA_l[o + 4096];
      aM0 = __builtin_amdgcn_mfma_f32_32x32x16_f16(a0, bh, aM0, 0, 0, 0);
      aM1 = __builtin_amdgcn_mfma_f32_32x32x16_f16(a1, bh, aM1, 0, 0, 0);
      aLa0 = __builtin_amdgcn_mfma_f32_32x32x16_f16(a0, bl, aLa0, 0, 0, 0);
      aLa1 = __builtin_amdgcn_mfma_f32_32x32x16_f16(a1, bl, aLa1, 0, 0, 0);
      aLb0 = __builtin_amdgcn_mfma_f32_32x32x16_f16(l0, bh, aLb0, 0, 0, 0);
      aLb1 = __builtin_amdgcn_mfma_f32_32x32x16_f16(l1, bh, aLb1, 0, 0, 0);
    }
    {
      const int l = lane & 31;
      const int rbase = 4 * (lane >> 5);
#pragma unroll
      for (int reg = 0; reg < 16; ++reg) {
        const int row = (reg & 3) + 8 * (reg >> 2) + rbase;
        cand[wv][row][l] = aM0[reg] + (aLa0[reg] + aLb0[reg]) * INV2048;
        cand[wv][row + 32][l] = aM1[reg] + (aLa1[reg] + aLb1[reg]) * INV2048;
      }
    }
    __syncthreads();
#pragma unroll
    for (int i = 0; i < 8; ++i) {
      const int idx = i * 256 + tid;
      const int b4 = (idx & 15) * 4;
      const int nl = idx >> 4;  // 0..127
      float4 o;
      o.x = cand[nl >> 5][b4 + 0][nl & 31];
      o.y = cand[nl >> 5][b4 + 1][nl & 31];
      o.z = cand[nl >> 5][b4 + 2][nl & 31];
      o.w = cand[nl >> 5][b4 + 3][nl & 31];
      *reinterpret_cast<float4*>(&preH[((long long)hhb * 128 + nl) * 64 + b4]) = o;
    }
    return;
  }

  // ---- logits part ----
  const int nt = blockIdx.x * 4 + wv;
  f32x16 accM0, accM1, accL0, accL1;
#pragma unroll
  for (int i = 0; i < 16; ++i) { accM0[i] = 0.f; accM1[i] = 0.f; accL0[i] = 0.f; accL1[i] = 0.f; }

  const f16x8* pAh0 = reinterpret_cast<const f16x8*>(Ahi) + lane;
  const f16x8* pAh1 = reinterpret_cast<const f16x8*>(Ahi) + 4096 + lane;
  const f16x8* pAl0 = reinterpret_cast<const f16x8*>(Alo) + lane;
  const f16x8* pAl1 = reinterpret_cast<const f16x8*>(Alo) + 4096 + lane;
  const f16x8* pBh = reinterpret_cast<const f16x8*>(WOhi) + (long long)nt * 4096 + lane;
  const f16x8* pBl = reinterpret_cast<const f16x8*>(WOlo) + (long long)nt * 4096 + lane;

#pragma unroll 4
  for (int ksi = 0; ksi < 64; ++ksi) {
    const int o = ksi * 64;
    f16x8 bh = pBh[o];
    f16x8 bl = pBl[o];
    f16x8 ah0 = pAh0[o];
    f16x8 ah1 = pAh1[o];
    f16x8 al0 = pAl0[o];
    f16x8 al1 = pAl1[o];
    accM0 = __builtin_amdgcn_mfma_f32_32x32x16_f16(ah0, bh, accM0, 0, 0, 0);
    accM1 = __builtin_amdgcn_mfma_f32_32x32x16_f16(ah1, bh, accM1, 0, 0, 0);
    accL0 = __builtin_amdgcn_mfma_f32_32x32x16_f16(ah0, bl, accL0, 0, 0, 0);
    accL1 = __builtin_amdgcn_mfma_f32_32x32x16_f16(ah1, bl, accL1, 0, 0, 0);
    accL0 = __builtin_amdgcn_mfma_f32_32x32x16_f16(al0, bh, accL0, 0, 0, 0);
    accL1 = __builtin_amdgcn_mfma_f32_32x32x16_f16(al1, bh, accL1, 0, 0, 0);
  }

  const int nn = nt * 32 + (lane & 31);
  const float bo = b_out[nn];
  const int rbase = 4 * (lane >> 5);
#pragma unroll
  for (int reg = 0; reg < 16; ++reg) {
    const int row0 = (reg & 3) + 8 * (reg >> 2) + rbase;
    const float v0 = accM0[reg] + accL0[reg] * INV2048 + bo;
    __builtin_nontemporal_store(v0, &out[(long long)row0 * (T_ * (long long)V_) + (long long)t * V_ + nn]);
    cand[wv][row0][lane & 31] = v0;
    const int row1 = row0 + 32;
    const float v1 = accM1[reg] + accL1[reg] * INV2048 + bo;
    __builtin_nontemporal_store(v1, &out[(long long)row1 * (T_ * (long long)V_) + (long long)t * V_ + nn]);
    cand[wv][row1][lane & 31] = v1;
  }
  __syncthreads();
  {
    const int w = tid >> 6, r = tid & 63;
    const int nb = (blockIdx.x * 4 + w) * 32;
    unsigned long long kk = 0ull;
#pragma unroll
    for (int l0 = 0; l0 < 32; ++l0) {
      const int l = (l0 + r) & 31;
      const float v = cand[w][r][l];
      unsigned u = __float_as_uint(v);
      u = (u & 0x80000000u) ? ~u : (u | 0x80000000u);
      const unsigned long long key = ((unsigned long long)u << 32) |
          (unsigned long long)(0xFFFFFFFFu - (unsigned)(nb + l));
      if (key > kk) kk = key;
    }
    wbest[w][r] = kk;
  }
  __syncthreads();
  if (tid < 64) {
    unsigned long long kk = wbest[0][tid];
#pragma unroll
    for (int w = 1; w < 4; ++w) { const unsigned long long q = wbest[w][tid]; if (q > kk) kk = q; }
    bestPart[(long long)tid * 256 + blockIdx.x] = kk;
  }
}

// ---------------------------------------------------------------------------
// mu / logvar / z from hT. grid = 64 x 256; wave = latent col l, lane = b.
// ---------------------------------------------------------------------------
__global__ __launch_bounds__(256) void k_mu_lv_z(
    const float* __restrict__ hT, const float* __restrict__ W_mu, const float* __restrict__ b_mu,
    const float* __restrict__ W_lv, const float* __restrict__ b_lv,
    const float* __restrict__ eps, float* __restrict__ out_mu, float* __restrict__ out_lv,
    float* __restrict__ zT)
{
  const int lane = threadIdx.x & 63;
  const int wv = __builtin_amdgcn_readfirstlane(threadIdx.x >> 6);
  const int l = blockIdx.x * 4 + wv;
  const float* wm = W_mu + (long long)l * H_;
  const float* wl = W_lv + (long long)l * H_;
  float am = 0.f, av = 0.f;
#pragma unroll 8
  for (int k = 0; k < H_; ++k) {
    const float h = hT[k * 64 + lane];
    am = fmaf(wm[k], h, am);
    av = fmaf(wl[k], h, av);
  }
  const float mu = am + b_mu[l];
  const float lv = av + b_lv[l];
  out_mu[lane * L_ + l] = mu;
  out_lv[lane * L_ + l] = lv;
  zT[l * 64 + lane] = fmaf(eps[lane * L_ + l], expf(0.5f * lv), mu);
}

// ---------------------------------------------------------------------------
// h_dec0 = z @ W_proj.T + b_proj. Writes hT0 + A-frags. grid = 256 x 256.
// ---------------------------------------------------------------------------
__global__ __launch_bounds__(256) void k_proj(
    const float* __restrict__ zT, const float* __restrict__ W_proj,
    const float* __restrict__ b_proj, float* __restrict__ hT0,
    f16* __restrict__ Aohi, f16* __restrict__ Aolo)
{
  const int lane = threadIdx.x & 63;
  const int wv = __builtin_amdgcn_readfirstlane(threadIdx.x >> 6);
  const int j = blockIdx.x * 4 + wv;
  const float* wr = W_proj + (long long)j * L_;
  float acc = 0.f;
#pragma unroll 8
  for (int k = 0; k < L_; ++k) acc = fmaf(wr[k], zT[k * 64 + lane], acc);
  const float hv = acc + b_proj[j];
  hT0[(long long)j * 64 + lane] = hv;
  write_frag(Aohi, Aolo, lane, j, hv);
}

// ---------------------------------------------------------------------------
extern "C" void kernel_launch(void* const* d_in, const int* in_sizes, int n_in,
                              void* d_out, int out_size, void* d_ws, size_t ws_size,
                              hipStream_t stream) {
  (void)in_sizes; (void)n_in; (void)out_size;
  const int*   x        = (const int*)d_in[0];
  const float* eps      = (const float*)d_in[1];
  const float* E        = (const float*)d_in[2];
  const float* W_ih_enc = (const float*)d_in[3];
  const float* W_hh_enc = (const float*)d_in[4];
  const float* b_ih_enc = (const float*)d_in[5];
  const float* b_hh_enc = (const float*)d_in[6];
  const float* W_mu     = (const float*)d_in[7];
  const float* b_mu     = (const float*)d_in[8];
  const float* W_lv     = (const float*)d_in[9];
  const float* b_lv     = (const float*)d_in[10];
  const float* W_proj   = (const float*)d_in[11];
  const float* b_proj   = (const float*)d_in[12];
  const float* W_ih_dec = (const float*)d_in[13];
  const float* W_hh_dec = (const float*)d_in[14];
  const float* b_ih_dec = (const float*)d_in[15];
  const float* b_hh_dec = (const float*)d_in[16];
  const float* W_out    = (const float*)d_in[17];
  const float* b_out    = (const float*)d_in[18];

  float* out = (float*)d_out;
  const long long OFF_MU = (long long)B_ * T_ * V_;
  const long long OFF_LV = OFF_MU + (long long)B_ * L_;

  // Workspace layout (float offsets)
  float* ws = (float*)d_ws;
  float* hA   = ws + 0;         // enc hT [1024][64]
  float* hB   = ws + 65536;
  float* dA   = ws + 131072;    // dec hT
  float* dB   = ws + 196608;
  float* zT   = ws + 262144;    // [256][64]
  unsigned long long* bestPart = (unsigned long long*)(ws + 278528);  // [64][256]
  float* preH = ws + 311296;    // [3072][64]
  f16* frAhi  = (f16*)(ws + 507904);   // h A-frags [2][64][64][8]
  f16* frAlo  = (f16*)(ws + 540672);
  f16* WHEhi  = (f16*)(ws + 638976);   // [96][64][64][8]
  f16* WHElo  = (f16*)(ws + 2211840);
  f16* WHDhi  = (f16*)(ws + 3784704);
  f16* WHDlo  = (f16*)(ws + 5357568);
  f16* WIEhi  = (f16*)(ws + 6930432);  // [96][32][64][8]
  f16* WIElo  = (f16*)(ws + 7716864);
  // time-multiplexed region: {XA frags + Gi} then {WO frags}
  f16* XAhi   = (f16*)(ws + 8503296);  // [128][32][64][8]
  f16* XAlo   = (f16*)(ws + 9551872);
  float* Gi   = ws + 10600448;         // [64][3072][64]
  f16* WOhi   = (f16*)(ws + 8503296);  // [1000][64][64][8] (after encoder)
  f16* WOlo   = (f16*)(ws + 24887296);
  const size_t WS_NEED = (size_t)41271296 * 4;
  if (ws_size < WS_NEED) return;

  hipMemsetAsync(hA, 0, (size_t)H_ * B_ * sizeof(float), stream);
  hipMemsetAsync(frAhi, 0, (size_t)2 * 65536 * sizeof(f16), stream);  // frAhi + frAlo
  hipMemsetAsync(bestPart, 0, (size_t)64 * 256 * 8, stream);

  // ---- one-time weight packs ----
  k_pack_wf<1024><<<3 * H_, 256, 0, stream>>>(W_hh_enc, WHEhi, WHElo);
  k_pack_wf<1024><<<3 * H_, 256, 0, stream>>>(W_hh_dec, WHDhi, WHDlo);
  k_pack_wf<512><<<3 * H_, 128, 0, stream>>>(W_ih_enc, WIEhi, WIElo);
  k_pack_xe<<<S_ * B_, 128, 0, stream>>>(x, E, XAhi, XAlo);

  // ---- encoder input gates (hoisted GEMM) ----
  k_gates_mfma<<<64 * 24, 256, 0, stream>>>(XAhi, XAlo, WIEhi, WIElo, b_ih_enc, Gi);

  // ---- encoder: 64 x (hh MFMA + apply) ----
  for (int t = 0; t < S_; ++t) {
    const float* hin = (t & 1) ? hB : hA;
    float* hout = (t & 1) ? hA : hB;
    k_hh_mfma<<<96, 256, 0, stream>>>(frAhi, frAlo, WHEhi, WHElo, preH);
    k_apply_enc<<<256, 256, 0, stream>>>(preH, Gi + (long long)t * 3 * H_ * B_,
                                         b_hh_enc, hin, hout, frAhi, frAlo);
  }
  // t=63 odd -> final h in hA

  // ---- latent ----
  k_mu_lv_z<<<64, 256, 0, stream>>>(hA, W_mu, b_mu, W_lv, b_lv, eps,
                                    out + OFF_MU, out + OFF_LV, zT);
  k_proj<<<256, 256, 0, stream>>>(zT, W_proj, b_proj, dA, frAhi, frAlo);

  // ---- pack W_out (overwrites XA+Gi region — both dead now) ----
  k_pack_wf<1024><<<V_, 256, 0, stream>>>(W_out, WOhi, WOlo);

  // ---- initial decoder hh from h_dec0 frags ----
  k_hh_mfma<<<96, 256, 0, stream>>>(frAhi, frAlo, WHDhi, WHDlo, preH);

  // ---- decoder: 64 x (apply + fused logits/hh) ----
  for (int t = 0; t < T_; ++t) {
    const float* hin = (t & 1) ? dB : dA;
    float* hout = (t & 1) ? dA : dB;
    if (t == 0) {
      k_dec_apply<0><<<256, 1024, 0, stream>>>(
          E, nullptr, W_ih_dec, b_ih_dec, b_hh_dec, preH, hin, hout, frAhi, frAlo);
    } else {
      k_dec_apply<2><<<256, 1024, 0, stream>>>(
          E, bestPart, W_ih_dec, b_ih_dec, b_hh_dec, preH, hin, hout, frAhi, frAlo);
    }
    k_logits_hh<<<274, 256, 0, stream>>>(frAhi, frAlo, WOhi, WOlo, WHDhi, WHDlo,
                                         b_out, out, bestPart, preH, t);
  }
}